// Round 7
// baseline (711.804 us; speedup 1.0000x reference)
//
#include <hip/hip_runtime.h>
#include <hip/hip_bf16.h>
#include <hip/hip_fp16.h>

typedef _Float16 f16;
typedef _Float16 f16x2 __attribute__((ext_vector_type(2)));
typedef _Float16 f16x4 __attribute__((ext_vector_type(4)));
typedef _Float16 f16x8 __attribute__((ext_vector_type(8)));
typedef float f32x4 __attribute__((ext_vector_type(4)));

#define BN_EPS 1e-5f

// ---------------- kernel 1: graph start offsets from sorted segment_ids ----------------
__global__ void seg_starts_k(const int* __restrict__ seg, int N, int G, int* __restrict__ start) {
    int n = blockIdx.x * blockDim.x + threadIdx.x;
    if (n >= N) return;
    int s = seg[n];
    int p = (n == 0) ? -1 : seg[n - 1];
    for (int g = p + 1; g <= s; ++g) start[g] = n;
    if (n == N - 1) {
        for (int g = s + 1; g <= G; ++g) start[g] = N;
    }
}

// ---------------- kernel 2: weight prep (BN folding, fp16 transpose) ----------------
__global__ void prep_k(const float* __restrict__ W1, const float* __restrict__ b1,
                       const float* __restrict__ W2, const float* __restrict__ b2,
                       const float* __restrict__ W3, const float* __restrict__ b3,
                       const float* __restrict__ oW1, const float* __restrict__ ob1,
                       const float* __restrict__ g1, const float* __restrict__ be1,
                       const float* __restrict__ rm1, const float* __restrict__ rv1,
                       const float* __restrict__ g2, const float* __restrict__ be2,
                       const float* __restrict__ rm2, const float* __restrict__ rv2,
                       const float* __restrict__ g3, const float* __restrict__ be3,
                       const float* __restrict__ rm3, const float* __restrict__ rv3,
                       f16* __restrict__ Wt, float* __restrict__ bp) {
    int T = gridDim.x;
    int t = blockIdx.x, l = blockIdx.y;
    int o = threadIdx.x;  // 0..127
    __shared__ float s_sh[128], c_sh[128];

    const float *W, *b, *gg = nullptr, *be = nullptr, *rm = nullptr, *rv = nullptr;
    if (l == 0)      { W = W1;  b = b1; }
    else if (l == 1) { W = W2;  b = b2;  gg = g1; be = be1; rm = rm1; rv = rv1; }
    else if (l == 2) { W = W3;  b = b3;  gg = g2; be = be2; rm = rm2; rv = rv2; }
    else             { W = oW1; b = ob1; gg = g3; be = be3; rm = rm3; rv = rv3; }

    float s = 1.f, c = 0.f;
    if (gg) {
        float sv = gg[t * 128 + o] * rsqrtf(rv[t * 128 + o] + BN_EPS);
        s = sv;
        c = be[t * 128 + o] - rm[t * 128 + o] * sv;
    }
    s_sh[o] = s;
    c_sh[o] = c;
    __syncthreads();

    const float* Wsrc = W + (size_t)t * 128 * 128;
    f16* Wdst = Wt + (((size_t)l * T + t) * 128 + o) * 128;  // [l][t][o][i]
    float acc = b[t * 128 + o];
    for (int i = 0; i < 128; ++i) {
        float wv = Wsrc[i * 128 + o];
        Wdst[i] = (f16)(s_sh[i] * wv);
        acc += c_sh[i] * wv;
    }
    bp[((size_t)l * T + t) * 128 + o] = acc;
}

// ---------------- kernel 3: transposed-slab pooling, vectorized LDS ----------------
// Block (256 thr, 4 waves) owns graphs starting in [A0, A0+64); stages an
// extended slab (<=128 rows) TRANSPOSED: xsT[f][atom] (f16, XOR-swizzled 16B
// slots). Weight phase reads row-major A-frags from GLOBAL (L2-hot) and writes
// wlsT[task][atom]. One barrier. Pooling per 32-atom tile: 1 ds_read_b128 (A,
// w-frag) + 8 ds_read_b128 (B, x-frags) + 8 MFMA 16x16x32. No scalar gathers.
__global__ __launch_bounds__(256) void pool4_k(const float* __restrict__ feats,
                                               const float* __restrict__ atom_w,
                                               const float* __restrict__ atom_b,
                                               const int* __restrict__ seg,
                                               const int* __restrict__ start,
                                               f16* __restrict__ mol, int N, int G) {
    __shared__ f16 xsT[128][128];   // [feature][atom] 32KB
    __shared__ f16 wlsT[16][128];   // [task][atom]    4KB

    int b = blockIdx.x;
    int A0 = b << 6;                 // 64-atom base
    int tid = threadIdx.x;
    int wave = tid >> 6, lane = tid & 63;
    int lr = lane & 15, kg = lane >> 4;
    int cnt = N - A0; if (cnt > 64) cnt = 64;

    int segPrev = (A0 > 0) ? seg[A0 - 1] : -1;
    int gLastSeg = seg[A0 + cnt - 1];
    int gFirst = segPrev + 1;
    int extEnd = start[gLastSeg + 1];
    int rows_need = extEnd - A0;
    if (rows_need < cnt) rows_need = cnt;
    if (rows_need > 128) rows_need = 128;    // max graph ~45 << 64 slack
    int gLast = (A0 + cnt >= N) ? (G - 1) : gLastSeg;
    int ntau = (rows_need + 15) >> 4;        // 16-row weight tiles (<=8)

    // B-fragment for weight MFMA: atom_w[t=lr][k = ks*32 + kg*8 + j]
    f16x8 bfr[4];
    float ab = 0.f;
#pragma unroll
    for (int ks = 0; ks < 4; ++ks) {
        f16x8 v = {};
        if (lr < 12) {
            const float* s = atom_w + lr * 128 + ks * 32 + kg * 8;
#pragma unroll
            for (int j = 0; j < 8; ++j) v[j] = (f16)s[j];
        }
        bfr[ks] = v;
    }
    if (lr < 12) ab = atom_b[lr];

    // 1) transposed staging. Wave-iter covers 16 atoms x 16 features.
    // lane -> (aq = lane>>4 atom-quad, fi = lane&15 feature). Zero-fill
    // beyond rows_need (NaN safety for masked MFMA operands).
    {
        int aq = lane >> 4, fi = lane & 15;
#pragma unroll 4
        for (int it = 0; it < 16; ++it) {
            int comb = wave + (it << 2);       // 0..63
            int ait = comb & 7, fblk = comb >> 3;
            int abase = (ait << 4) + (aq << 2);
            int f = (fblk << 4) + fi;
            const float* src = feats + (size_t)(A0 + abase) * 128 + f;
            float v0 = 0.f, v1 = 0.f, v2 = 0.f, v3 = 0.f;
            if (abase + 0 < rows_need) v0 = src[0];
            if (abase + 1 < rows_need) v1 = src[128];
            if (abase + 2 < rows_need) v2 = src[256];
            if (abase + 3 < rows_need) v3 = src[384];
            f16x4 h;
            h[0] = (f16)v0; h[1] = (f16)v1; h[2] = (f16)v2; h[3] = (f16)v3;
            int slot = (ait << 1) + (aq >> 1);
            *(f16x4*)(&xsT[f][((slot ^ (f & 7)) << 3) + ((aq & 1) << 2)]) = h;
        }
    }

    // 2) weight phase (global reads, no xsT dependency -> overlaps staging)
#pragma unroll
    for (int tt = 0; tt < 2; ++tt) {
        int tau = wave + (tt << 2);
        if (tau < ntau) {
            f32x4 pa = {0.f, 0.f, 0.f, 0.f};
            int arow = (tau << 4) + lr;
            bool rv = arow < rows_need;
            const float* src = feats + (size_t)(A0 + arow) * 128 + (kg << 3);
#pragma unroll
            for (int ks = 0; ks < 4; ++ks) {
                f16x8 afr = {};
                if (rv) {
                    float4 u0 = *(const float4*)(src + ks * 32);
                    float4 u1 = *(const float4*)(src + ks * 32 + 4);
                    afr[0] = (f16)u0.x; afr[1] = (f16)u0.y;
                    afr[2] = (f16)u0.z; afr[3] = (f16)u0.w;
                    afr[4] = (f16)u1.x; afr[5] = (f16)u1.y;
                    afr[6] = (f16)u1.z; afr[7] = (f16)u1.w;
                }
                pa = __builtin_amdgcn_mfma_f32_16x16x32_f16(afr, bfr[ks], pa, 0, 0, 0);
            }
            // D: col = lane&15 = task(lr), row = kg*4+j = atom-in-tile
            f16x4 wv;
#pragma unroll
            for (int j = 0; j < 4; ++j) {
                float w = (lr < 12) ? 1.f / (1.f + __expf(-(pa[j] + ab))) : 0.f;
                wv[j] = (f16)w;
            }
            int slot = (tau << 1) + (kg >> 1);
            *(f16x4*)(&wlsT[lr][((slot ^ (lr & 7)) << 3) + ((kg & 1) << 2)]) = wv;
        }
    }
    __syncthreads();

    // 3) pooling: whole graphs round-robin, 32-atom tiles, all-b128 reads
    for (int g = gFirst + wave; g <= gLast; g += 4) {
        int s = start[g], e = start[g + 1];
        int lls = s - A0; if (lls < 0) lls = 0;
        int lle = e - A0; if (lle > rows_need) lle = rows_need;

        f32x4 acc[8];
#pragma unroll
        for (int nf = 0; nf < 8; ++nf) acc[nf] = (f32x4){0.f, 0.f, 0.f, 0.f};

        if (lls < lle) {
            int ta = lls >> 5, tb = (lle - 1) >> 5;
            for (int tp = ta; tp <= tb; ++tp) {
                int aslot = (tp << 2) + kg;   // ((tp*32 + kg*8) >> 3)
                // A-frag: w[task=lr][atoms tp*32 + kg*8 + jj]
                f16x8 a2 = *(const f16x8*)(&wlsT[lr][(aslot ^ (lr & 7)) << 3]);
                int ab0 = (tp << 5) + (kg << 3);
#pragma unroll
                for (int jj = 0; jj < 8; ++jj) {
                    int la = ab0 + jj;
                    if (la < lls || la >= lle) a2[jj] = (f16)0.f;
                }
#pragma unroll
                for (int nf = 0; nf < 8; ++nf) {
                    int f = (nf << 4) + lr;
                    f16x8 b2 = *(const f16x8*)(&xsT[f][(aslot ^ (f & 7)) << 3]);
                    acc[nf] = __builtin_amdgcn_mfma_f32_16x16x32_f16(a2, b2, acc[nf], 0, 0, 0);
                }
            }
        }

        // store mol[t][g][f]: D col = lane&15 = f-part(lr), row = kg*4+j = task
        if (kg < 3) {
#pragma unroll
            for (int nf = 0; nf < 8; ++nf)
#pragma unroll
                for (int j = 0; j < 4; ++j)
                    mol[((size_t)((kg << 2) + j) * G + g) * 128 + (nf << 4) + lr] =
                        (f16)acc[nf][j];
        }
    }
}

// ---------------- kernel 4: fused 4-layer MLP + final dot, fp16 MFMA ----------------
// mol layout [t][g][f]. (unchanged from round 6)
__global__ __launch_bounds__(256, 2) void fc_k(const f16* __restrict__ mol,
                                               const f16* __restrict__ Wt,
                                               const float* __restrict__ bp,
                                               const float* __restrict__ oW2,
                                               const float* __restrict__ ob2,
                                               float* __restrict__ out, int G, int T) {
    __shared__ f16 A[2][64][128];
    __shared__ f16 B[128][128];

    int t = blockIdx.y;
    int g0 = blockIdx.x * 64;
    int tid = threadIdx.x;

    {
        const f16* src = mol + (size_t)t * G * 128;
#pragma unroll
        for (int k = 0; k < 4; ++k) {
            int c = tid + k * 256;          // 0..1023
            int r = c >> 4, sl = c & 15;
            uint4 v = make_uint4(0u, 0u, 0u, 0u);
            if (g0 + r < G) v = *(const uint4*)(src + (size_t)(g0 + r) * 128 + sl * 8);
            *(uint4*)(&A[0][r][(sl ^ (r & 7)) * 8]) = v;
        }
    }
    {
        const f16* src = Wt + ((size_t)0 * T + t) * 128 * 128;
#pragma unroll
        for (int k = 0; k < 8; ++k) {
            int c = tid + k * 256;          // 0..2047
            int r = c >> 4, sl = c & 15;
            uint4 v = *(const uint4*)(src + (size_t)r * 128 + sl * 8);
            *(uint4*)(&B[r][(sl ^ (r & 7)) * 8]) = v;
        }
    }
    __syncthreads();

    int wid = tid >> 6, lane = tid & 63;
    int lg = lane >> 4, lr = lane & 15;
    int m0 = wid * 16;
    int arow = m0 + lr;
    float pred[4] = {0.f, 0.f, 0.f, 0.f};
    int cur = 0;

    for (int l = 0; l < 4; ++l) {
        f16x8 afr[4];
#pragma unroll
        for (int ks = 0; ks < 4; ++ks) {
            int sl = (4 * ks + lg) ^ (arow & 7);
            afr[ks] = *(const f16x8*)(&A[cur][arow][sl * 8]);
        }
        const float* bias = bp + ((size_t)l * T + t) * 128;
#pragma unroll
        for (int nf = 0; nf < 8; ++nf) {
            int n = nf * 16 + lr;
            f32x4 acc = {0.f, 0.f, 0.f, 0.f};
#pragma unroll
            for (int ks = 0; ks < 4; ++ks) {
                int sl = (4 * ks + lg) ^ (n & 7);
                f16x8 bfr = *(const f16x8*)(&B[n][sl * 8]);
                acc = __builtin_amdgcn_mfma_f32_16x16x32_f16(afr[ks], bfr, acc, 0, 0, 0);
            }
            float bv = bias[n];
            if (l < 3) {
#pragma unroll
                for (int j = 0; j < 4; ++j) {
                    float y = acc[j] + bv;
                    y = y > 0.f ? y : 0.f;
                    int rr = m0 + 4 * lg + j;
                    A[cur ^ 1][rr][(((n >> 3) ^ (rr & 7)) << 3) + (n & 7)] = (f16)y;
                }
            } else {
                float w2 = oW2[t * 128 + n];
#pragma unroll
                for (int j = 0; j < 4; ++j) {
                    float z = acc[j] + bv;
                    z = z > 0.f ? z : 0.f;
                    pred[j] += z * w2;
                }
            }
        }
        __syncthreads();
        if (l < 3) {
            const f16* src = Wt + ((size_t)(l + 1) * T + t) * 128 * 128;
#pragma unroll
            for (int k = 0; k < 8; ++k) {
                int c = tid + k * 256;
                int r = c >> 4, sl = c & 15;
                uint4 v = *(const uint4*)(src + (size_t)r * 128 + sl * 8);
                *(uint4*)(&B[r][(sl ^ (r & 7)) * 8]) = v;
            }
            __syncthreads();
            cur ^= 1;
        }
    }

#pragma unroll
    for (int m = 1; m < 16; m <<= 1) {
#pragma unroll
        for (int j = 0; j < 4; ++j) pred[j] += __shfl_xor(pred[j], m, 64);
    }
    if (lr == 0) {
        float ob = ob2[t];
#pragma unroll
        for (int j = 0; j < 4; ++j) {
            int gg = g0 + m0 + 4 * lg + j;
            if (gg < G) out[(size_t)gg * T + t] = pred[j] + ob;
        }
    }
}

extern "C" void kernel_launch(void* const* d_in, const int* in_sizes, int n_in,
                              void* d_out, int out_size, void* d_ws, size_t ws_size,
                              hipStream_t stream) {
    const float* node_feats = (const float*)d_in[0];
    const int*   seg        = (const int*)d_in[1];
    const float* atom_w     = (const float*)d_in[3];
    const float* atom_b     = (const float*)d_in[4];
    const float* W1  = (const float*)d_in[5];
    const float* b1  = (const float*)d_in[6];
    const float* g1  = (const float*)d_in[7];
    const float* be1 = (const float*)d_in[8];
    const float* rm1 = (const float*)d_in[9];
    const float* rv1 = (const float*)d_in[10];
    const float* W2  = (const float*)d_in[11];
    const float* b2  = (const float*)d_in[12];
    const float* g2  = (const float*)d_in[13];
    const float* be2 = (const float*)d_in[14];
    const float* rm2 = (const float*)d_in[15];
    const float* rv2 = (const float*)d_in[16];
    const float* W3  = (const float*)d_in[17];
    const float* b3  = (const float*)d_in[18];
    const float* g3  = (const float*)d_in[19];
    const float* be3 = (const float*)d_in[20];
    const float* rm3 = (const float*)d_in[21];
    const float* rv3 = (const float*)d_in[22];
    const float* oW1 = (const float*)d_in[23];
    const float* ob1 = (const float*)d_in[24];
    const float* oW2 = (const float*)d_in[25];
    const float* ob2 = (const float*)d_in[26];

    int T = in_sizes[4];          // 12
    int F = in_sizes[3] / T;      // 128
    int N = in_sizes[0] / F;      // 1,000,000
    int G = out_size / T;         // 50,000
    int nb = (N + 63) / 64;       // pooling blocks (64-atom base)

    char* ws = (char*)d_ws;
    size_t off = 0;
    int* start = (int*)ws;
    off += (((size_t)(G + 1) * 4) + 255) & ~(size_t)255;
    f16* Wt = (f16*)(ws + off);
    off += (((size_t)4 * T * 128 * 128 * 2) + 255) & ~(size_t)255;
    float* bp = (float*)(ws + off);
    off += (((size_t)4 * T * 128 * 4) + 255) & ~(size_t)255;
    f16* mol = (f16*)(ws + off);

    seg_starts_k<<<(N + 255) / 256, 256, 0, stream>>>(seg, N, G, start);
    prep_k<<<dim3(T, 4), 128, 0, stream>>>(W1, b1, W2, b2, W3, b3, oW1, ob1,
                                           g1, be1, rm1, rv1,
                                           g2, be2, rm2, rv2,
                                           g3, be3, rm3, rv3, Wt, bp);
    pool4_k<<<nb, 256, 0, stream>>>(node_feats, atom_w, atom_b, seg, start, mol, N, G);
    fc_k<<<dim3((G + 63) / 64, T), 256, 0, stream>>>(mol, Wt, bp, oW2, ob2,
                                                     (float*)d_out, G, T);
}

// Round 8
// 387.448 us; speedup vs baseline: 1.8372x; 1.8372x over previous
//
#include <hip/hip_runtime.h>
#include <hip/hip_bf16.h>
#include <hip/hip_fp16.h>

typedef _Float16 f16;
typedef _Float16 f16x2 __attribute__((ext_vector_type(2)));
typedef _Float16 f16x4 __attribute__((ext_vector_type(4)));
typedef _Float16 f16x8 __attribute__((ext_vector_type(8)));
typedef float f32x4 __attribute__((ext_vector_type(4)));

#define BN_EPS 1e-5f

// ---------------- kernel 1: graph start offsets from sorted segment_ids ----------------
__global__ void seg_starts_k(const int* __restrict__ seg, int N, int G, int* __restrict__ start) {
    int n = blockIdx.x * blockDim.x + threadIdx.x;
    if (n >= N) return;
    int s = seg[n];
    int p = (n == 0) ? -1 : seg[n - 1];
    for (int g = p + 1; g <= s; ++g) start[g] = n;
    if (n == N - 1) {
        for (int g = s + 1; g <= G; ++g) start[g] = N;
    }
}

// ---------------- kernel 2: weight prep (BN folding, fp16 transpose) ----------------
__global__ void prep_k(const float* __restrict__ W1, const float* __restrict__ b1,
                       const float* __restrict__ W2, const float* __restrict__ b2,
                       const float* __restrict__ W3, const float* __restrict__ b3,
                       const float* __restrict__ oW1, const float* __restrict__ ob1,
                       const float* __restrict__ g1, const float* __restrict__ be1,
                       const float* __restrict__ rm1, const float* __restrict__ rv1,
                       const float* __restrict__ g2, const float* __restrict__ be2,
                       const float* __restrict__ rm2, const float* __restrict__ rv2,
                       const float* __restrict__ g3, const float* __restrict__ be3,
                       const float* __restrict__ rm3, const float* __restrict__ rv3,
                       f16* __restrict__ Wt, float* __restrict__ bp) {
    int T = gridDim.x;
    int t = blockIdx.x, l = blockIdx.y;
    int o = threadIdx.x;  // 0..127
    __shared__ float s_sh[128], c_sh[128];

    const float *W, *b, *gg = nullptr, *be = nullptr, *rm = nullptr, *rv = nullptr;
    if (l == 0)      { W = W1;  b = b1; }
    else if (l == 1) { W = W2;  b = b2;  gg = g1; be = be1; rm = rm1; rv = rv1; }
    else if (l == 2) { W = W3;  b = b3;  gg = g2; be = be2; rm = rm2; rv = rv2; }
    else             { W = oW1; b = ob1; gg = g3; be = be3; rm = rm3; rv = rv3; }

    float s = 1.f, c = 0.f;
    if (gg) {
        float sv = gg[t * 128 + o] * rsqrtf(rv[t * 128 + o] + BN_EPS);
        s = sv;
        c = be[t * 128 + o] - rm[t * 128 + o] * sv;
    }
    s_sh[o] = s;
    c_sh[o] = c;
    __syncthreads();

    const float* Wsrc = W + (size_t)t * 128 * 128;
    f16* Wdst = Wt + (((size_t)l * T + t) * 128 + o) * 128;  // [l][t][o][i]
    float acc = b[t * 128 + o];
    for (int i = 0; i < 128; ++i) {
        float wv = Wsrc[i * 128 + o];
        Wdst[i] = (f16)(s_sh[i] * wv);
        acc += c_sh[i] * wv;
    }
    bp[((size_t)l * T + t) * 128 + o] = acc;
}

// ---------------- kernel 3: zero-LDS fused pooling (pool5) ----------------
// One wave per graph. Per 16-atom chunk, ALL from global (no LDS, no barriers):
//  - B-frags: 32 dword loads x[atom][f] (16 lanes x consecutive f32 = 64B segs)
//  - A-frags: 8 float4 loads of the same rows (16B granule, L1-hit after B)
//  - w-chain: 4x mfma_16x16x32(x_rowmajor, atom_w) -> pa[atom][task]
//    pa D-frag (row=atom,col=task) IS the A-frag (row=task,k=atom) of 16x16x16
//  - pool: 8x mfma_16x16x16(sigmoid(pa) masked, x_colmajor) -> acc[t][f]
// Tail: clamp row addresses to e-1; mask via a2=0. Empty graph -> zero store.
// mol layout [t][g][f].
__global__ __launch_bounds__(256) void pool5_k(const float* __restrict__ feats,
                                               const float* __restrict__ atom_w,
                                               const float* __restrict__ atom_b,
                                               const int* __restrict__ start,
                                               f16* __restrict__ mol, int G) {
    int wave = threadIdx.x >> 6, lane = threadIdx.x & 63;
    int g = blockIdx.x * 4 + wave;
    if (g >= G) return;
    int lr = lane & 15, kg = lane >> 4;

    // atom_w B-frag: aw[t=lr][k = ks*32 + kg*8 + j], tasks 12..15 zero
    f16x8 bfr[4];
    float ab = 0.f;
#pragma unroll
    for (int ks = 0; ks < 4; ++ks) {
        f16x8 v = {};
        if (lr < 12) {
            const float* s = atom_w + lr * 128 + ks * 32 + kg * 8;
#pragma unroll
            for (int j = 0; j < 8; ++j) v[j] = (f16)s[j];
        }
        bfr[ks] = v;
    }
    if (lr < 12) ab = atom_b[lr];

    f32x4 acc[8];
#pragma unroll
    for (int nf = 0; nf < 8; ++nf) acc[nf] = (f32x4){0.f, 0.f, 0.f, 0.f};

    int s = start[g], e = start[g + 1];

    for (int c0 = s; c0 < e; c0 += 16) {
        // ---- B-frag rows (atoms kg*4+j), clamped to e-1 ----
        int rB[4];
#pragma unroll
        for (int j = 0; j < 4; ++j) {
            int a = c0 + (kg << 2) + j;
            rB[j] = (a < e) ? a : (e - 1);
        }
        // 32 coalesced dword loads: bx[fb][j] = feats[rB[j]][fb*16 + lr]
        float bx[8][4];
#pragma unroll
        for (int j = 0; j < 4; ++j) {
            const float* pB = feats + (size_t)rB[j] * 128 + lr;
#pragma unroll
            for (int fb = 0; fb < 8; ++fb) bx[fb][j] = pB[fb << 4];
        }

        // ---- A-frag row (atom lr), clamped; 8 float4 (L1-hot lines) ----
        int rA = c0 + lr; if (rA >= e) rA = e - 1;
        const float* pA = feats + (size_t)rA * 128 + (kg << 3);
        f32x4 pa = {0.f, 0.f, 0.f, 0.f};
#pragma unroll
        for (int ks = 0; ks < 4; ++ks) {
            float4 u0 = *(const float4*)(pA + (ks << 5));
            float4 u1 = *(const float4*)(pA + (ks << 5) + 4);
            f16x8 afr;
            afr[0] = (f16)u0.x; afr[1] = (f16)u0.y; afr[2] = (f16)u0.z; afr[3] = (f16)u0.w;
            afr[4] = (f16)u1.x; afr[5] = (f16)u1.y; afr[6] = (f16)u1.z; afr[7] = (f16)u1.w;
            pa = __builtin_amdgcn_mfma_f32_16x16x32_f16(afr, bfr[ks], pa, 0, 0, 0);
        }

        // ---- sigmoid + tail mask: a2[j] = w[task=lr][atom=c0+kg*4+j] ----
        f16x4 a2;
#pragma unroll
        for (int j = 0; j < 4; ++j) {
            float w = 1.f / (1.f + __expf(-(pa[j] + ab)));
            int a = c0 + (kg << 2) + j;
            a2[j] = (a < e) ? (f16)w : (f16)0.f;
        }

        // ---- pooling MFMAs: acc[fb][t][f] += w^T x ----
#pragma unroll
        for (int fb = 0; fb < 8; ++fb) {
            f16x4 b2;
#pragma unroll
            for (int j = 0; j < 4; ++j) b2[j] = (f16)bx[fb][j];
            acc[fb] = __builtin_amdgcn_mfma_f32_16x16x16f16(a2, b2, acc[fb], 0, 0, 0);
        }
    }

    // store mol[t][g][f]: D row = kg*4+j = t (kg<3), col = lr = f-in-block
    if (kg < 3) {
#pragma unroll
        for (int fb = 0; fb < 8; ++fb)
#pragma unroll
            for (int j = 0; j < 4; ++j)
                mol[((size_t)((kg << 2) + j) * G + g) * 128 + (fb << 4) + lr] =
                    (f16)acc[fb][j];
    }
}

// ---------------- kernel 4: fused 4-layer MLP + final dot, fp16 MFMA ----------------
// mol layout [t][g][f]. (unchanged)
__global__ __launch_bounds__(256, 2) void fc_k(const f16* __restrict__ mol,
                                               const f16* __restrict__ Wt,
                                               const float* __restrict__ bp,
                                               const float* __restrict__ oW2,
                                               const float* __restrict__ ob2,
                                               float* __restrict__ out, int G, int T) {
    __shared__ f16 A[2][64][128];
    __shared__ f16 B[128][128];

    int t = blockIdx.y;
    int g0 = blockIdx.x * 64;
    int tid = threadIdx.x;

    {
        const f16* src = mol + (size_t)t * G * 128;
#pragma unroll
        for (int k = 0; k < 4; ++k) {
            int c = tid + k * 256;          // 0..1023
            int r = c >> 4, sl = c & 15;
            uint4 v = make_uint4(0u, 0u, 0u, 0u);
            if (g0 + r < G) v = *(const uint4*)(src + (size_t)(g0 + r) * 128 + sl * 8);
            *(uint4*)(&A[0][r][(sl ^ (r & 7)) * 8]) = v;
        }
    }
    {
        const f16* src = Wt + ((size_t)0 * T + t) * 128 * 128;
#pragma unroll
        for (int k = 0; k < 8; ++k) {
            int c = tid + k * 256;          // 0..2047
            int r = c >> 4, sl = c & 15;
            uint4 v = *(const uint4*)(src + (size_t)r * 128 + sl * 8);
            *(uint4*)(&B[r][(sl ^ (r & 7)) * 8]) = v;
        }
    }
    __syncthreads();

    int wid = tid >> 6, lane = tid & 63;
    int lg = lane >> 4, lr = lane & 15;
    int m0 = wid * 16;
    int arow = m0 + lr;
    float pred[4] = {0.f, 0.f, 0.f, 0.f};
    int cur = 0;

    for (int l = 0; l < 4; ++l) {
        f16x8 afr[4];
#pragma unroll
        for (int ks = 0; ks < 4; ++ks) {
            int sl = (4 * ks + lg) ^ (arow & 7);
            afr[ks] = *(const f16x8*)(&A[cur][arow][sl * 8]);
        }
        const float* bias = bp + ((size_t)l * T + t) * 128;
#pragma unroll
        for (int nf = 0; nf < 8; ++nf) {
            int n = nf * 16 + lr;
            f32x4 acc = {0.f, 0.f, 0.f, 0.f};
#pragma unroll
            for (int ks = 0; ks < 4; ++ks) {
                int sl = (4 * ks + lg) ^ (n & 7);
                f16x8 bfr = *(const f16x8*)(&B[n][sl * 8]);
                acc = __builtin_amdgcn_mfma_f32_16x16x32_f16(afr[ks], bfr, acc, 0, 0, 0);
            }
            float bv = bias[n];
            if (l < 3) {
#pragma unroll
                for (int j = 0; j < 4; ++j) {
                    float y = acc[j] + bv;
                    y = y > 0.f ? y : 0.f;
                    int rr = m0 + 4 * lg + j;
                    A[cur ^ 1][rr][(((n >> 3) ^ (rr & 7)) << 3) + (n & 7)] = (f16)y;
                }
            } else {
                float w2 = oW2[t * 128 + n];
#pragma unroll
                for (int j = 0; j < 4; ++j) {
                    float z = acc[j] + bv;
                    z = z > 0.f ? z : 0.f;
                    pred[j] += z * w2;
                }
            }
        }
        __syncthreads();
        if (l < 3) {
            const f16* src = Wt + ((size_t)(l + 1) * T + t) * 128 * 128;
#pragma unroll
            for (int k = 0; k < 8; ++k) {
                int c = tid + k * 256;
                int r = c >> 4, sl = c & 15;
                uint4 v = *(const uint4*)(src + (size_t)r * 128 + sl * 8);
                *(uint4*)(&B[r][(sl ^ (r & 7)) * 8]) = v;
            }
            __syncthreads();
            cur ^= 1;
        }
    }

#pragma unroll
    for (int m = 1; m < 16; m <<= 1) {
#pragma unroll
        for (int j = 0; j < 4; ++j) pred[j] += __shfl_xor(pred[j], m, 64);
    }
    if (lr == 0) {
        float ob = ob2[t];
#pragma unroll
        for (int j = 0; j < 4; ++j) {
            int gg = g0 + m0 + 4 * lg + j;
            if (gg < G) out[(size_t)gg * T + t] = pred[j] + ob;
        }
    }
}

extern "C" void kernel_launch(void* const* d_in, const int* in_sizes, int n_in,
                              void* d_out, int out_size, void* d_ws, size_t ws_size,
                              hipStream_t stream) {
    const float* node_feats = (const float*)d_in[0];
    const int*   seg        = (const int*)d_in[1];
    const float* atom_w     = (const float*)d_in[3];
    const float* atom_b     = (const float*)d_in[4];
    const float* W1  = (const float*)d_in[5];
    const float* b1  = (const float*)d_in[6];
    const float* g1  = (const float*)d_in[7];
    const float* be1 = (const float*)d_in[8];
    const float* rm1 = (const float*)d_in[9];
    const float* rv1 = (const float*)d_in[10];
    const float* W2  = (const float*)d_in[11];
    const float* b2  = (const float*)d_in[12];
    const float* g2  = (const float*)d_in[13];
    const float* be2 = (const float*)d_in[14];
    const float* rm2 = (const float*)d_in[15];
    const float* rv2 = (const float*)d_in[16];
    const float* W3  = (const float*)d_in[17];
    const float* b3  = (const float*)d_in[18];
    const float* g3  = (const float*)d_in[19];
    const float* be3 = (const float*)d_in[20];
    const float* rm3 = (const float*)d_in[21];
    const float* rv3 = (const float*)d_in[22];
    const float* oW1 = (const float*)d_in[23];
    const float* ob1 = (const float*)d_in[24];
    const float* oW2 = (const float*)d_in[25];
    const float* ob2 = (const float*)d_in[26];

    int T = in_sizes[4];          // 12
    int F = in_sizes[3] / T;      // 128
    int N = in_sizes[0] / F;      // 1,000,000
    int G = out_size / T;         // 50,000

    char* ws = (char*)d_ws;
    size_t off = 0;
    int* start = (int*)ws;
    off += (((size_t)(G + 1) * 4) + 255) & ~(size_t)255;
    f16* Wt = (f16*)(ws + off);
    off += (((size_t)4 * T * 128 * 128 * 2) + 255) & ~(size_t)255;
    float* bp = (float*)(ws + off);
    off += (((size_t)4 * T * 128 * 4) + 255) & ~(size_t)255;
    f16* mol = (f16*)(ws + off);

    seg_starts_k<<<(N + 255) / 256, 256, 0, stream>>>(seg, N, G, start);
    prep_k<<<dim3(T, 4), 128, 0, stream>>>(W1, b1, W2, b2, W3, b3, oW1, ob1,
                                           g1, be1, rm1, rv1,
                                           g2, be2, rm2, rv2,
                                           g3, be3, rm3, rv3, Wt, bp);
    pool5_k<<<(G + 3) / 4, 256, 0, stream>>>(node_feats, atom_w, atom_b, start, mol, G);
    fc_k<<<dim3((G + 63) / 64, T), 256, 0, stream>>>(mol, Wt, bp, oW2, ob2,
                                                     (float*)d_out, G, T);
}

// Round 10
// 348.846 us; speedup vs baseline: 2.0405x; 1.1107x over previous
//
#include <hip/hip_runtime.h>
#include <hip/hip_bf16.h>
#include <hip/hip_fp16.h>

typedef _Float16 f16;
typedef _Float16 f16x2 __attribute__((ext_vector_type(2)));
typedef _Float16 f16x4 __attribute__((ext_vector_type(4)));
typedef _Float16 f16x8 __attribute__((ext_vector_type(8)));
typedef float f32x4 __attribute__((ext_vector_type(4)));

typedef __attribute__((address_space(1))) const void gas_t;
typedef __attribute__((address_space(3))) void las_t;

#define BN_EPS 1e-5f

// ---------------- kernel 1: graph start offsets from sorted segment_ids ----------------
__global__ void seg_starts_k(const int* __restrict__ seg, int N, int G, int* __restrict__ start) {
    int n = blockIdx.x * blockDim.x + threadIdx.x;
    if (n >= N) return;
    int s = seg[n];
    int p = (n == 0) ? -1 : seg[n - 1];
    for (int g = p + 1; g <= s; ++g) start[g] = n;
    if (n == N - 1) {
        for (int g = s + 1; g <= G; ++g) start[g] = N;
    }
}

// ---------------- kernel 2: weight prep (BN folding, fp16, PRE-SWIZZLED) ----------------
// Wt[l][t][o][ (slot ^ (o&7))*8 + low ] so fc can stage it LINEARLY via
// global_load_lds while reads stay slot-XOR-swizzled (rule #21 pattern).
__global__ void prep_k(const float* __restrict__ W1, const float* __restrict__ b1,
                       const float* __restrict__ W2, const float* __restrict__ b2,
                       const float* __restrict__ W3, const float* __restrict__ b3,
                       const float* __restrict__ oW1, const float* __restrict__ ob1,
                       const float* __restrict__ g1, const float* __restrict__ be1,
                       const float* __restrict__ rm1, const float* __restrict__ rv1,
                       const float* __restrict__ g2, const float* __restrict__ be2,
                       const float* __restrict__ rm2, const float* __restrict__ rv2,
                       const float* __restrict__ g3, const float* __restrict__ be3,
                       const float* __restrict__ rm3, const float* __restrict__ rv3,
                       f16* __restrict__ Wt, float* __restrict__ bp) {
    int T = gridDim.x;
    int t = blockIdx.x, l = blockIdx.y;
    int o = threadIdx.x;  // 0..127
    __shared__ float s_sh[128], c_sh[128];

    const float *W, *b, *gg = nullptr, *be = nullptr, *rm = nullptr, *rv = nullptr;
    if (l == 0)      { W = W1;  b = b1; }
    else if (l == 1) { W = W2;  b = b2;  gg = g1; be = be1; rm = rm1; rv = rv1; }
    else if (l == 2) { W = W3;  b = b3;  gg = g2; be = be2; rm = rm2; rv = rv2; }
    else             { W = oW1; b = ob1; gg = g3; be = be3; rm = rm3; rv = rv3; }

    float s = 1.f, c = 0.f;
    if (gg) {
        float sv = gg[t * 128 + o] * rsqrtf(rv[t * 128 + o] + BN_EPS);
        s = sv;
        c = be[t * 128 + o] - rm[t * 128 + o] * sv;
    }
    s_sh[o] = s;
    c_sh[o] = c;
    __syncthreads();

    const float* Wsrc = W + (size_t)t * 128 * 128;
    f16* Wdst = Wt + (((size_t)l * T + t) * 128 + o) * 128;  // row o, swizzled cols
    float acc = b[t * 128 + o];
    for (int i = 0; i < 128; ++i) {
        float wv = Wsrc[i * 128 + o];
        Wdst[(((i >> 3) ^ (o & 7)) << 3) + (i & 7)] = (f16)(s_sh[i] * wv);
        acc += c_sh[i] * wv;
    }
    bp[((size_t)l * T + t) * 128 + o] = acc;
}

// ---------------- kernel 3: zero-LDS fused pooling (pool5, store swizzled) ----------------
__global__ __launch_bounds__(256) void pool5_k(const float* __restrict__ feats,
                                               const float* __restrict__ atom_w,
                                               const float* __restrict__ atom_b,
                                               const int* __restrict__ start,
                                               f16* __restrict__ mol, int G) {
    int wave = threadIdx.x >> 6, lane = threadIdx.x & 63;
    int g = blockIdx.x * 4 + wave;
    if (g >= G) return;
    int lr = lane & 15, kg = lane >> 4;

    f16x8 bfr[4];
    float ab = 0.f;
#pragma unroll
    for (int ks = 0; ks < 4; ++ks) {
        f16x8 v = {};
        if (lr < 12) {
            const float* s = atom_w + lr * 128 + ks * 32 + kg * 8;
#pragma unroll
            for (int j = 0; j < 8; ++j) v[j] = (f16)s[j];
        }
        bfr[ks] = v;
    }
    if (lr < 12) ab = atom_b[lr];

    f32x4 acc[8];
#pragma unroll
    for (int nf = 0; nf < 8; ++nf) acc[nf] = (f32x4){0.f, 0.f, 0.f, 0.f};

    int s = start[g], e = start[g + 1];

    for (int c0 = s; c0 < e; c0 += 16) {
        int rB[4];
#pragma unroll
        for (int j = 0; j < 4; ++j) {
            int a = c0 + (kg << 2) + j;
            rB[j] = (a < e) ? a : (e - 1);
        }
        float bx[8][4];
#pragma unroll
        for (int j = 0; j < 4; ++j) {
            const float* pB = feats + (size_t)rB[j] * 128 + lr;
#pragma unroll
            for (int fb = 0; fb < 8; ++fb) bx[fb][j] = pB[fb << 4];
        }

        int rA = c0 + lr; if (rA >= e) rA = e - 1;
        const float* pA = feats + (size_t)rA * 128 + (kg << 3);
        f32x4 pa = {0.f, 0.f, 0.f, 0.f};
#pragma unroll
        for (int ks = 0; ks < 4; ++ks) {
            float4 u0 = *(const float4*)(pA + (ks << 5));
            float4 u1 = *(const float4*)(pA + (ks << 5) + 4);
            f16x8 afr;
            afr[0] = (f16)u0.x; afr[1] = (f16)u0.y; afr[2] = (f16)u0.z; afr[3] = (f16)u0.w;
            afr[4] = (f16)u1.x; afr[5] = (f16)u1.y; afr[6] = (f16)u1.z; afr[7] = (f16)u1.w;
            pa = __builtin_amdgcn_mfma_f32_16x16x32_f16(afr, bfr[ks], pa, 0, 0, 0);
        }

        f16x4 a2;
#pragma unroll
        for (int j = 0; j < 4; ++j) {
            float w = 1.f / (1.f + __expf(-(pa[j] + ab)));
            int a = c0 + (kg << 2) + j;
            a2[j] = (a < e) ? (f16)w : (f16)0.f;
        }

#pragma unroll
        for (int fb = 0; fb < 8; ++fb) {
            f16x4 b2;
#pragma unroll
            for (int j = 0; j < 4; ++j) b2[j] = (f16)bx[fb][j];
            acc[fb] = __builtin_amdgcn_mfma_f32_16x16x16f16(a2, b2, acc[fb], 0, 0, 0);
        }
    }

    // store mol[t][g][ swz(f) ]: slot = f>>3, position = (slot ^ (g&7))*8 + (f&7)
    if (kg < 3) {
        int gx = g & 7;
#pragma unroll
        for (int fb = 0; fb < 8; ++fb) {
            int slot = (fb << 1) + (lr >> 3);
            int fi = (((slot ^ gx)) << 3) + (lr & 7);
#pragma unroll
            for (int j = 0; j < 4; ++j)
                mol[((size_t)((kg << 2) + j) * G + g) * 128 + fi] = (f16)acc[fb][j];
        }
    }
}

// ---------------- kernel 4: fused 4-layer MLP, gload_lds staging, 48KB LDS ----------------
// FIXED vs round 9: per-layer order is now vmcnt(0) -> barrier -> afr ds_reads
// -> MFMA nf-loop (in-place A writes, own-wave stripe) -> barrier -> async B
// restage. Round 9 read afr BEFORE the staging drain (cross-wave LDS race).
__global__ __launch_bounds__(256, 3) void fc_k(const f16* __restrict__ mol,
                                               const f16* __restrict__ Wt,
                                               const float* __restrict__ bp,
                                               const float* __restrict__ oW2,
                                               const float* __restrict__ ob2,
                                               float* __restrict__ out, int G, int T) {
    __shared__ f16 A[64][128];
    __shared__ f16 B[128][128];

    int t = blockIdx.y;
    int g0 = blockIdx.x * 64;
    int tid = threadIdx.x;
    int wid = tid >> 6, lane = tid & 63;

    // prologue: stage A (16 x 1KB chunks) and B layer-0 (32 x 1KB chunks)
    {
        const f16* aplane = mol + (size_t)t * G * 128;
#pragma unroll
        for (int i = 0; i < 4; ++i) {
            int c = wid + (i << 2);                 // chunk 0..15
            int r = (c << 2) + (lane >> 4);
            int row = g0 + r; if (row >= G) row = G - 1;
            const f16* src = aplane + (size_t)row * 128 + ((lane & 15) << 3);
            __builtin_amdgcn_global_load_lds((gas_t*)src,
                (las_t*)((char*)&A[0][0] + c * 1024), 16, 0, 0);
        }
        const f16* bsrc = Wt + ((size_t)0 * T + t) * 16384;
#pragma unroll
        for (int i = 0; i < 8; ++i) {
            int c = wid + (i << 2);                 // chunk 0..31
            int r = (c << 2) + (lane >> 4);
            const f16* src = bsrc + (size_t)r * 128 + ((lane & 15) << 3);
            __builtin_amdgcn_global_load_lds((gas_t*)src,
                (las_t*)((char*)&B[0][0] + c * 1024), 16, 0, 0);
        }
    }

    int lg = lane >> 4, lr = lane & 15;
    int m0 = wid * 16;
    int arow = m0 + lr;
    float pred[4] = {0.f, 0.f, 0.f, 0.f};

    for (int l = 0; l < 4; ++l) {
        asm volatile("s_waitcnt vmcnt(0)" ::: "memory");   // own staging landed
        __syncthreads();                                   // all waves' staging visible

        // afr reads AFTER the drain (own 16-row stripe; DS per-wave in-order
        // makes the later in-place writes safe)
        f16x8 afr[4];
#pragma unroll
        for (int ks = 0; ks < 4; ++ks) {
            int sl = (4 * ks + lg) ^ (arow & 7);
            afr[ks] = *(const f16x8*)(&A[arow][sl * 8]);
        }

        const float* bias = bp + ((size_t)l * T + t) * 128;
#pragma unroll
        for (int nf = 0; nf < 8; ++nf) {
            int n = nf * 16 + lr;
            f32x4 acc = {0.f, 0.f, 0.f, 0.f};
#pragma unroll
            for (int ks = 0; ks < 4; ++ks) {
                int sl = (4 * ks + lg) ^ (n & 7);
                f16x8 bfr = *(const f16x8*)(&B[n][sl * 8]);
                acc = __builtin_amdgcn_mfma_f32_16x16x32_f16(afr[ks], bfr, acc, 0, 0, 0);
            }
            float bv = bias[n];
            if (l < 3) {
#pragma unroll
                for (int j = 0; j < 4; ++j) {
                    float y = acc[j] + bv;
                    y = y > 0.f ? y : 0.f;
                    int rr = m0 + 4 * lg + j;
                    A[rr][(((n >> 3) ^ (rr & 7)) << 3) + (n & 7)] = (f16)y;
                }
            } else {
                float w2 = oW2[t * 128 + n];
#pragma unroll
                for (int j = 0; j < 4; ++j) {
                    float z = acc[j] + bv;
                    z = z > 0.f ? z : 0.f;
                    pred[j] += z * w2;
                }
            }
        }
        __syncthreads();                                   // all waves done reading B
        if (l < 3) {
            const f16* bsrc = Wt + ((size_t)(l + 1) * T + t) * 16384;
#pragma unroll
            for (int i = 0; i < 8; ++i) {
                int c = wid + (i << 2);
                int r = (c << 2) + (lane >> 4);
                const f16* src = bsrc + (size_t)r * 128 + ((lane & 15) << 3);
                __builtin_amdgcn_global_load_lds((gas_t*)src,
                    (las_t*)((char*)&B[0][0] + c * 1024), 16, 0, 0);
            }
        }
    }

#pragma unroll
    for (int m = 1; m < 16; m <<= 1) {
#pragma unroll
        for (int j = 0; j < 4; ++j) pred[j] += __shfl_xor(pred[j], m, 64);
    }
    if (lr == 0) {
        float ob = ob2[t];
#pragma unroll
        for (int j = 0; j < 4; ++j) {
            int gg = g0 + m0 + 4 * lg + j;
            if (gg < G) out[(size_t)gg * T + t] = pred[j] + ob;
        }
    }
}

extern "C" void kernel_launch(void* const* d_in, const int* in_sizes, int n_in,
                              void* d_out, int out_size, void* d_ws, size_t ws_size,
                              hipStream_t stream) {
    const float* node_feats = (const float*)d_in[0];
    const int*   seg        = (const int*)d_in[1];
    const float* atom_w     = (const float*)d_in[3];
    const float* atom_b     = (const float*)d_in[4];
    const float* W1  = (const float*)d_in[5];
    const float* b1  = (const float*)d_in[6];
    const float* g1  = (const float*)d_in[7];
    const float* be1 = (const float*)d_in[8];
    const float* rm1 = (const float*)d_in[9];
    const float* rv1 = (const float*)d_in[10];
    const float* W2  = (const float*)d_in[11];
    const float* b2  = (const float*)d_in[12];
    const float* g2  = (const float*)d_in[13];
    const float* be2 = (const float*)d_in[14];
    const float* rm2 = (const float*)d_in[15];
    const float* rv2 = (const float*)d_in[16];
    const float* W3  = (const float*)d_in[17];
    const float* b3  = (const float*)d_in[18];
    const float* g3  = (const float*)d_in[19];
    const float* be3 = (const float*)d_in[20];
    const float* rm3 = (const float*)d_in[21];
    const float* rv3 = (const float*)d_in[22];
    const float* oW1 = (const float*)d_in[23];
    const float* ob1 = (const float*)d_in[24];
    const float* oW2 = (const float*)d_in[25];
    const float* ob2 = (const float*)d_in[26];

    int T = in_sizes[4];          // 12
    int F = in_sizes[3] / T;      // 128
    int N = in_sizes[0] / F;      // 1,000,000
    int G = out_size / T;         // 50,000

    char* ws = (char*)d_ws;
    size_t off = 0;
    int* start = (int*)ws;
    off += (((size_t)(G + 1) * 4) + 255) & ~(size_t)255;
    f16* Wt = (f16*)(ws + off);
    off += (((size_t)4 * T * 128 * 128 * 2) + 255) & ~(size_t)255;
    float* bp = (float*)(ws + off);
    off += (((size_t)4 * T * 128 * 4) + 255) & ~(size_t)255;
    f16* mol = (f16*)(ws + off);

    seg_starts_k<<<(N + 255) / 256, 256, 0, stream>>>(seg, N, G, start);
    prep_k<<<dim3(T, 4), 128, 0, stream>>>(W1, b1, W2, b2, W3, b3, oW1, ob1,
                                           g1, be1, rm1, rv1,
                                           g2, be2, rm2, rv2,
                                           g3, be3, rm3, rv3, Wt, bp);
    pool5_k<<<(G + 3) / 4, 256, 0, stream>>>(node_feats, atom_w, atom_b, start, mol, G);
    fc_k<<<dim3((G + 63) / 64, T), 256, 0, stream>>>(mol, Wt, bp, oW2, ob2,
                                                     (float*)d_out, G, T);
}